// Round 3
// baseline (342.960 us; speedup 1.0000x reference)
//
#include <hip/hip_runtime.h>

// Problem constants (from reference)
#define DIM_IN   2048
#define FEAT     128
#define KP1      16385      // NCE_N + 1
#define NDATA    100000
#define BATCH    64
#define RT       256        // rows per block tile in dense gemm
#define NTILES   ((NDATA + RT - 1) / RT)   // 391
#define GCH      8          // k-chunks per (side,b) in gather/loss kernels

constexpr float NCE_T_INV = 1.0f / 0.07f;
constexpr float M_CONST   = 16384.0f / 100000.0f;   // NCE_N / N_DATA
constexpr float EPS_C     = 1e-7f;

// ---------------------------------------------------------------------------
// Kernel 1: h = l2norm(feat @ w.T + b) for both sides. (unchanged)
// ---------------------------------------------------------------------------
__global__ void __launch_bounds__(256) embed_kernel(
    const float* __restrict__ feat_s, const float* __restrict__ feat_t,
    const float* __restrict__ w_s, const float* __restrict__ b_s,
    const float* __restrict__ w_t, const float* __restrict__ b_t,
    float* __restrict__ v_out)
{
    const int blk  = blockIdx.x;      // side*64 + b
    const int side = blk >> 6;
    const int b    = blk & 63;
    const float* feat = (side == 0 ? feat_s : feat_t) + (size_t)b * DIM_IN;
    const float* w    = (side == 0 ? w_s : w_t);
    const float* bias = (side == 0 ? b_s : b_t);

    __shared__ float sfeat[DIM_IN];
    __shared__ float part[2][FEAT];
    __shared__ float wsum[2];

    const int t = threadIdx.x;
    {
        const float4* f4 = (const float4*)feat;
        float4* s4 = (float4*)sfeat;
        for (int j = t; j < DIM_IN / 4; j += 256) s4[j] = f4[j];
    }
    __syncthreads();

    const int d = t & 127, half = t >> 7;
    const float4* w4 = (const float4*)(w + (size_t)d * DIM_IN + half * (DIM_IN / 2));
    const float*  sf = sfeat + half * (DIM_IN / 2);
    float acc = 0.f;
#pragma unroll 8
    for (int j = 0; j < DIM_IN / 8; ++j) {
        float4 wv = w4[j];
        acc += wv.x * sf[4*j] + wv.y * sf[4*j+1] + wv.z * sf[4*j+2] + wv.w * sf[4*j+3];
    }
    part[half][d] = acc;
    __syncthreads();

    if (t < 128) {
        float pre = part[0][t] + part[1][t] + bias[t];
        part[0][t] = pre;
        float sq = pre * pre;
#pragma unroll
        for (int o = 32; o > 0; o >>= 1) sq += __shfl_xor(sq, o, 64);
        if ((t & 63) == 0) wsum[t >> 6] = sq;
    }
    __syncthreads();
    if (t < 128) {
        float inv_norm = 1.0f / sqrtf(wsum[0] + wsum[1]);
        v_out[(size_t)blk * FEAT + t] = part[0][t] * inv_norm;
    }
}

// ---------------------------------------------------------------------------
// Kernel 2: dense skinny GEMM + exp, transposed output.
// E[sb][n] = exp( dot(bank_side[n], v[sb]) / T ), sb = side*64 + b.
// A (bank rows) has ZERO k-reuse -> streamed global->VGPR, never LDS.
// B (64 anchors x 128 k = 32 KB) staged once in LDS as sB[k][64];
// reads are 2-address broadcast b128 -> conflict-free.
// Thread: 8 consecutive rows x 8 anchors (acc 64), 256 thr = 256 rows x 64.
// Per k-chunk(4): 8 global float4 (A), 8 ds_read_b128 (B), 256 FMA
//   -> 0.5 B LDS/FMA-lane: VALU-bound (~21 us FMA floor vs ~10 us LDS).
// ---------------------------------------------------------------------------
__global__ void __launch_bounds__(256) gemm_exp_kernel(
    const float* __restrict__ mem_v1, const float* __restrict__ mem_v2,
    const float* __restrict__ v_in, float* __restrict__ E)
{
    __shared__ __align__(16) float sB[FEAT * 64];   // sB[k*64 + b], 32 KB

    const int bx   = blockIdx.x;
    const int side = bx & 1;
    const int tile = bx >> 1;
    const int n0   = tile * RT;
    const float* bank = (side == 0 ? mem_v2 : mem_v1);
    const float* vb   = v_in + (size_t)side * 64 * FEAT;
    const int t = threadIdx.x;

    // stage B transposed: sB[k][b] = v[b][k]; lanes vary b -> consecutive
    // banks on the scalar writes (conflict-free).
    for (int i = t; i < 64 * 32; i += 256) {
        const int b2 = i & 63;        // anchor
        const int f  = i >> 6;        // float4 index in k
        float4 v4 = ((const float4*)vb)[b2 * 32 + f];
        sB[(f * 4 + 0) * 64 + b2] = v4.x;
        sB[(f * 4 + 1) * 64 + b2] = v4.y;
        sB[(f * 4 + 2) * 64 + b2] = v4.z;
        sB[(f * 4 + 3) * 64 + b2] = v4.w;
    }
    __syncthreads();

    const int ag = t >> 5;            // anchor group: anchors ag*8..ag*8+7
    const int rg = t & 31;            // row group: rows n0+rg*8..+7
    const int b0 = ag * 8;
    const int r0 = n0 + rg * 8;
    const int r0c = (r0 <= NDATA - 8) ? r0 : (NDATA - 8);  // clamp tail (NDATA%8==0)

    const float4* Abase = (const float4*)bank + (size_t)r0c * (FEAT / 4);

    float acc[8][8];
#pragma unroll
    for (int i = 0; i < 8; ++i)
#pragma unroll
        for (int j = 0; j < 8; ++j) acc[i][j] = 0.f;

    float4 a_cur[8], a_nxt[8];
#pragma unroll
    for (int i = 0; i < 8; ++i) a_cur[i] = Abase[i * 32];

    for (int kc = 0; kc < 32; ++kc) {
        if (kc < 31) {
#pragma unroll
            for (int i = 0; i < 8; ++i) a_nxt[i] = Abase[i * 32 + kc + 1];
        }
        const float* sBk = &sB[kc * 4 * 64];
#pragma unroll
        for (int c = 0; c < 4; ++c) {
            float4 blo = *(const float4*)&sBk[c * 64 + b0];
            float4 bhi = *(const float4*)&sBk[c * 64 + b0 + 4];
#pragma unroll
            for (int i = 0; i < 8; ++i) {
                const float a = (c == 0) ? a_cur[i].x : (c == 1) ? a_cur[i].y
                              : (c == 2) ? a_cur[i].z : a_cur[i].w;
                acc[i][0] += a * blo.x;  acc[i][1] += a * blo.y;
                acc[i][2] += a * blo.z;  acc[i][3] += a * blo.w;
                acc[i][4] += a * bhi.x;  acc[i][5] += a * bhi.y;
                acc[i][6] += a * bhi.z;  acc[i][7] += a * bhi.w;
            }
        }
#pragma unroll
        for (int i = 0; i < 8; ++i) a_cur[i] = a_nxt[i];
    }

    // epilogue: exp + transposed store E[sb][n]; thread rows contiguous ->
    // 2x float4 per anchor, fully-dense 2KB per (ag-group, anchor) store.
    if (r0 <= NDATA - 8) {
#pragma unroll
        for (int j = 0; j < 8; ++j) {
            float4 o0, o1;
            o0.x = __expf(acc[0][j] * NCE_T_INV);
            o0.y = __expf(acc[1][j] * NCE_T_INV);
            o0.z = __expf(acc[2][j] * NCE_T_INV);
            o0.w = __expf(acc[3][j] * NCE_T_INV);
            o1.x = __expf(acc[4][j] * NCE_T_INV);
            o1.y = __expf(acc[5][j] * NCE_T_INV);
            o1.z = __expf(acc[6][j] * NCE_T_INV);
            o1.w = __expf(acc[7][j] * NCE_T_INV);
            float* dst = E + (size_t)(side * 64 + b0 + j) * NDATA + r0;
            *(float4*)dst = o0;
            *(float4*)(dst + 4) = o1;
        }
    }
}

// ---------------------------------------------------------------------------
// Kernel 3: gather ex = E[sb][idx[b,k]], store compact, accumulate Z.
// blk&127 = sb keeps all chunks of one sb on one XCD (L2 window 400 KB).
// ---------------------------------------------------------------------------
__global__ void __launch_bounds__(256) gather_z_kernel(
    const int* __restrict__ sample_idx, const float* __restrict__ E,
    float* __restrict__ ex_out, float* __restrict__ z_out)
{
    const int blk   = blockIdx.x;
    const int chunk = blk >> 7;          // 0..GCH-1
    const int sb    = blk & 127;         // side*64 + b
    const int b     = sb & 63;
    const float* Eb = E + (size_t)sb * NDATA;

    float zp = 0.f;
    for (int k = chunk * 256 + threadIdx.x; k < KP1; k += GCH * 256) {
        const int idx = sample_idx[(size_t)b * KP1 + k];
        const float e = Eb[idx];
        ex_out[(size_t)sb * KP1 + k] = e;
        zp += e;
    }
#pragma unroll
    for (int o = 32; o > 0; o >>= 1) zp += __shfl_xor(zp, o, 64);
    __shared__ float zw[4];
    if ((threadIdx.x & 63) == 0) zw[threadIdx.x >> 6] = zp;
    __syncthreads();
    if (threadIdx.x == 0) atomicAdd(&z_out[sb >> 6], zw[0] + zw[1] + zw[2] + zw[3]);
}

// ---------------------------------------------------------------------------
// Kernel 4: loss from compact ex + Z. 1024 blocks (sb x 8 chunks).
// ---------------------------------------------------------------------------
__global__ void __launch_bounds__(256) loss_kernel(
    const float* __restrict__ ex_in, const float* __restrict__ z_in,
    float* __restrict__ out)
{
    const int blk   = blockIdx.x;
    const int chunk = blk >> 7;
    const int sb    = blk & 127;
    const float z   = z_in[sb >> 6] * ((float)NDATA / (64.0f * (float)KP1));
    const float rz  = 1.0f / z;
    const float* ex = ex_in + (size_t)sb * KP1;

    float part = 0.f;
    for (int k = chunk * 256 + threadIdx.x; k < KP1; k += GCH * 256) {
        const float x = ex[k] * rz;
        if (k == 0) part += __logf(x / (x + M_CONST + EPS_C));
        else        part += __logf(M_CONST / (x + M_CONST + EPS_C));
    }
#pragma unroll
    for (int o = 32; o > 0; o >>= 1) part += __shfl_xor(part, o, 64);
    __shared__ float pw[4];
    if ((threadIdx.x & 63) == 0) pw[threadIdx.x >> 6] = part;
    __syncthreads();
    if (threadIdx.x == 0)
        atomicAdd(out, -(pw[0] + pw[1] + pw[2] + pw[3]) * (1.0f / 64.0f));
}

// ---------------------------------------------------------------------------
extern "C" void kernel_launch(void* const* d_in, const int* in_sizes, int n_in,
                              void* d_out, int out_size, void* d_ws, size_t ws_size,
                              hipStream_t stream)
{
    const float* feat_s     = (const float*)d_in[0];
    const float* feat_t     = (const float*)d_in[1];
    /* d_in[2] = idx, unused: sample_idx[:,0] already holds it */
    const int*   sample_idx = (const int*)  d_in[3];
    const float* w_s        = (const float*)d_in[4];
    const float* b_s        = (const float*)d_in[5];
    const float* w_t        = (const float*)d_in[6];
    const float* b_t        = (const float*)d_in[7];
    const float* mem_v1     = (const float*)d_in[8];
    const float* mem_v2     = (const float*)d_in[9];
    float* out = (float*)d_out;

    // Workspace layout:
    //   [z: 2 f32][pad to 256]
    //   [v: 2*64*128 f32 = 64 KB]
    //   [ex: 2*64*16385 f32 = 8.39 MB]
    //   [E: 128*100000 f32 = 51.2 MB]  (transposed: E[sb][n])
    char*  ws    = (char*)d_ws;
    float* ws_z  = (float*)ws;
    float* ws_v  = (float*)(ws + 256);
    float* ws_ex = (float*)(ws + 256 + 2 * BATCH * FEAT * sizeof(float));
    float* ws_E  = (float*)(ws + 256 + 2 * BATCH * FEAT * sizeof(float)
                               + (size_t)2 * BATCH * KP1 * sizeof(float));

    hipMemsetAsync(ws_z, 0, 2 * sizeof(float), stream);
    hipMemsetAsync(out, 0, sizeof(float), stream);

    embed_kernel<<<2 * BATCH, 256, 0, stream>>>(feat_s, feat_t, w_s, b_s, w_t, b_t, ws_v);
    gemm_exp_kernel<<<2 * NTILES, 256, 0, stream>>>(mem_v1, mem_v2, ws_v, ws_E);
    gather_z_kernel<<<2 * BATCH * GCH, 256, 0, stream>>>(sample_idx, ws_E, ws_ex, ws_z);
    loss_kernel<<<2 * BATCH * GCH, 256, 0, stream>>>(ws_ex, ws_z, out);
}

// Round 4
// 261.407 us; speedup vs baseline: 1.3120x; 1.3120x over previous
//
#include <hip/hip_runtime.h>

// Problem constants (from reference)
#define DIM_IN   2048
#define FEAT     128
#define KP1      16385      // NCE_N + 1
#define NDATA    100000
#define BATCH    64
#define RT       256        // rows per gemm tile
#define NTILES   ((NDATA + RT - 1) / RT)   // 391
#define GCH      8          // k-chunks per (side,b) in gather kernel

constexpr float NCE_T_INV = 1.0f / 0.07f;
constexpr float M_CONST   = 16384.0f / 100000.0f;   // NCE_N / N_DATA
constexpr float EPS_C     = 1e-7f;

// ---------------------------------------------------------------------------
// Kernel 1: h = l2norm(feat @ w.T + b).
// REWRITE: per-wave coalesced row dots. Old version had lanes reading w at
// 4 KB stride (64 lines per instruction). Now: wave w handles d = w,w+4,...;
// 64 lanes read 64 consecutive float4 of w[d] (1 KB dense per instruction),
// dot against LDS-staged feat row, 6-shfl wave reduction.
// ---------------------------------------------------------------------------
__global__ void __launch_bounds__(256) embed_kernel(
    const float* __restrict__ feat_s, const float* __restrict__ feat_t,
    const float* __restrict__ w_s, const float* __restrict__ b_s,
    const float* __restrict__ w_t, const float* __restrict__ b_t,
    float* __restrict__ v_out)
{
    const int blk  = blockIdx.x;      // side*64 + b
    const int side = blk >> 6;
    const int b    = blk & 63;
    const float* feat = (side == 0 ? feat_s : feat_t) + (size_t)b * DIM_IN;
    const float* w    = (side == 0 ? w_s : w_t);
    const float* bias = (side == 0 ? b_s : b_t);

    __shared__ float sfeat[DIM_IN];
    __shared__ float pre[FEAT];
    __shared__ float wsum[2];

    const int t = threadIdx.x;
    {   // coalesced float4 stage of the feat row (8 KB)
        const float4* f4 = (const float4*)feat;
        float4* s4 = (float4*)sfeat;
        for (int j = t; j < DIM_IN / 4; j += 256) s4[j] = f4[j];
    }
    __syncthreads();

    const int wv = t >> 6, ln = t & 63;
    const float4* w4  = (const float4*)w;
    const float4* sf4 = (const float4*)sfeat;
    for (int d = wv; d < FEAT; d += 4) {
        float s = 0.f;
#pragma unroll
        for (int seg = 0; seg < 8; ++seg) {      // 512 float4 per row / 64 lanes
            float4 a = w4[d * (DIM_IN / 4) + seg * 64 + ln];
            float4 f = sf4[seg * 64 + ln];
            s += a.x * f.x + a.y * f.y + a.z * f.z + a.w * f.w;
        }
#pragma unroll
        for (int o = 32; o > 0; o >>= 1) s += __shfl_xor(s, o, 64);
        if (ln == 0) pre[d] = s;
    }
    __syncthreads();

    if (t < 128) {
        float p = pre[t] + bias[t];
        pre[t] = p;
        float sq = p * p;
#pragma unroll
        for (int o = 32; o > 0; o >>= 1) sq += __shfl_xor(sq, o, 64);
        if ((t & 63) == 0) wsum[t >> 6] = sq;
    }
    __syncthreads();
    if (t < 128) {
        float inv_norm = 1.0f / sqrtf(wsum[0] + wsum[1]);
        v_out[(size_t)blk * FEAT + t] = pre[t] * inv_norm;
    }
}

// ---------------------------------------------------------------------------
// Kernel 2: dense skinny GEMM + exp. E[sb][n] = exp(dot(bank[n], v[sb])/T).
// Structure: 256-row x 64-anchor tile, K split in two 64-wide passes.
//  - A staged global->LDS COALESCED (16 lanes read 256 B dense per row pair),
//    stored XOR-SWIZZLED: float4 f of row r lands at column f ^ ((r>>3)&7).
//    Inner-loop A reads then start at bank 4*((c^rg)&7) -> 8 distinct starts
//    covering all 32 banks, 8 lanes broadcast each => conflict-free.
//  - sB[k][64]: reads 2-way aliased = free.
//  - Thread tile 8 rows x 8 anchors (64 acc). Per 4k-chunk: 16 ds_read_b128
//    vs 256 v_fma -> VALU-bound. LDS 80 KB -> 2 blocks/CU.
// ---------------------------------------------------------------------------
__global__ void __launch_bounds__(256, 2) gemm_exp_kernel(
    const float* __restrict__ mem_v1, const float* __restrict__ mem_v2,
    const float* __restrict__ v_in, float* __restrict__ E)
{
    __shared__ __align__(16) float sA[RT * 64];   // swizzled [row][k4 ^ ((row>>3)&7)]
    __shared__ __align__(16) float sB[64 * 64];   // [k][b]

    const int bx   = blockIdx.x;
    const int side = bx & 1;
    const int tile = bx >> 1;
    const int n0   = tile * RT;
    const float* bank = (side == 0 ? mem_v2 : mem_v1);
    const float* vb   = v_in + (size_t)side * 64 * FEAT;
    const int t  = threadIdx.x;
    const int ag = t & 7;             // anchor group: anchors ag*8..+7
    const int rg = t >> 3;            // row group:    rows n0+rg*8..+7
    const int r0 = n0 + rg * 8;

    float acc[8][8];
#pragma unroll
    for (int i = 0; i < 8; ++i)
#pragma unroll
        for (int j = 0; j < 8; ++j) acc[i][j] = 0.f;

    for (int kp = 0; kp < 2; ++kp) {
        if (kp) __syncthreads();      // pass-0 compute done before restage
        // stage A: 4096 float4, 16/thread, coalesced (16 lanes = 256 B dense)
#pragma unroll
        for (int it = 0; it < 16; ++it) {
            const int i = t + it * 256;
            const int r = i >> 4;                 // tile-local row 0..255
            const int f = i & 15;                 // float4 index in k-half
            int row = n0 + r; if (row > NDATA - 1) row = NDATA - 1;
            float4 a = ((const float4*)(bank + (size_t)row * FEAT + kp * 64))[f];
            const int fs = f ^ ((r >> 3) & 7);    // xor swizzle
            *(float4*)&sA[r * 64 + fs * 4] = a;
        }
        // stage B: sB[k][b] = v[b][kp*64+k]; scalar writes bank=b -> free
#pragma unroll
        for (int it = 0; it < 4; ++it) {
            const int i  = t + it * 256;
            const int b2 = i & 63;
            const int f  = i >> 6;                // 0..15
            float4 v4 = *(const float4*)(vb + (size_t)b2 * FEAT + kp * 64 + f * 4);
            sB[(f * 4 + 0) * 64 + b2] = v4.x;
            sB[(f * 4 + 1) * 64 + b2] = v4.y;
            sB[(f * 4 + 2) * 64 + b2] = v4.z;
            sB[(f * 4 + 3) * 64 + b2] = v4.w;
        }
        __syncthreads();

#pragma unroll 1
        for (int c = 0; c < 16; ++c) {            // 16 chunks of 4 k
            float4 af[8], bf[8];
            const int ca = (c ^ (rg & 7)) * 4;    // un-swizzle
#pragma unroll
            for (int i = 0; i < 8; ++i)
                af[i] = *(const float4*)&sA[(rg * 8 + i) * 64 + ca];
#pragma unroll
            for (int kk = 0; kk < 4; ++kk) {
                bf[kk * 2 + 0] = *(const float4*)&sB[(c * 4 + kk) * 64 + ag * 8];
                bf[kk * 2 + 1] = *(const float4*)&sB[(c * 4 + kk) * 64 + ag * 8 + 4];
            }
#pragma unroll
            for (int kk = 0; kk < 4; ++kk) {
#pragma unroll
                for (int i = 0; i < 8; ++i) {
                    const float a = (kk == 0) ? af[i].x : (kk == 1) ? af[i].y
                                  : (kk == 2) ? af[i].z : af[i].w;
                    acc[i][0] += a * bf[kk * 2].x;
                    acc[i][1] += a * bf[kk * 2].y;
                    acc[i][2] += a * bf[kk * 2].z;
                    acc[i][3] += a * bf[kk * 2].w;
                    acc[i][4] += a * bf[kk * 2 + 1].x;
                    acc[i][5] += a * bf[kk * 2 + 1].y;
                    acc[i][6] += a * bf[kk * 2 + 1].z;
                    acc[i][7] += a * bf[kk * 2 + 1].w;
                }
            }
        }
    }

    // epilogue: exp + store E[sb][n]; thread rows consecutive -> per anchor a
    // wave's 8 same-ag lanes cover 64 consecutive n (coalesced 256 B).
    if (r0 + 8 <= NDATA) {
#pragma unroll
        for (int j = 0; j < 8; ++j) {
            float4 o0, o1;
            o0.x = __expf(acc[0][j] * NCE_T_INV);
            o0.y = __expf(acc[1][j] * NCE_T_INV);
            o0.z = __expf(acc[2][j] * NCE_T_INV);
            o0.w = __expf(acc[3][j] * NCE_T_INV);
            o1.x = __expf(acc[4][j] * NCE_T_INV);
            o1.y = __expf(acc[5][j] * NCE_T_INV);
            o1.z = __expf(acc[6][j] * NCE_T_INV);
            o1.w = __expf(acc[7][j] * NCE_T_INV);
            float* dst = E + (size_t)(side * 64 + ag * 8 + j) * NDATA + r0;
            *(float4*)dst = o0;
            *(float4*)(dst + 4) = o1;
        }
    }
}

// ---------------------------------------------------------------------------
// Kernel 3: gather ex = E[sb][idx[b,k]], store compact, accumulate Z[sb].
// blk&127 = sb keeps a given sb's chunks on one XCD. Z split per-sb: only
// 8 atomics per address (kills serialization risk on 2 hot addresses).
// ---------------------------------------------------------------------------
__global__ void __launch_bounds__(256) gather_z_kernel(
    const int* __restrict__ sample_idx, const float* __restrict__ E,
    float* __restrict__ ex_out, float* __restrict__ z_out)
{
    const int blk   = blockIdx.x;
    const int chunk = blk >> 7;          // 0..GCH-1
    const int sb    = blk & 127;         // side*64 + b
    const int b     = sb & 63;
    const float* Eb = E + (size_t)sb * NDATA;

    float zp = 0.f;
    for (int k = chunk * 256 + threadIdx.x; k < KP1; k += GCH * 256) {
        const int idx = sample_idx[(size_t)b * KP1 + k];
        const float e = Eb[idx];
        ex_out[(size_t)sb * KP1 + k] = e;
        zp += e;
    }
#pragma unroll
    for (int o = 32; o > 0; o >>= 1) zp += __shfl_xor(zp, o, 64);
    __shared__ float zw[4];
    if ((threadIdx.x & 63) == 0) zw[threadIdx.x >> 6] = zp;
    __syncthreads();
    if (threadIdx.x == 0) atomicAdd(&z_out[sb], zw[0] + zw[1] + zw[2] + zw[3]);
}

// ---------------------------------------------------------------------------
// Kernel 4: loss. 256 blocks (2 chunks x 128 sb). Z summed in-kernel from
// the 64 per-sb partials of this side; 256 output atomics total.
// ---------------------------------------------------------------------------
__global__ void __launch_bounds__(256) loss_kernel(
    const float* __restrict__ ex_in, const float* __restrict__ z_in,
    float* __restrict__ out)
{
    const int blk   = blockIdx.x;
    const int chunk = blk >> 7;          // 0..1
    const int sb    = blk & 127;
    const int side  = sb >> 6;

    __shared__ float zsh;
    if (threadIdx.x < 64) {
        float zv = z_in[side * 64 + threadIdx.x];
#pragma unroll
        for (int o = 32; o > 0; o >>= 1) zv += __shfl_xor(zv, o, 64);
        if (threadIdx.x == 0) zsh = zv;
    }
    __syncthreads();

    const float z  = zsh * ((float)NDATA / (64.0f * (float)KP1));
    const float rz = 1.0f / z;
    const float* ex = ex_in + (size_t)sb * KP1;

    float part = 0.f;
    for (int k = chunk * 256 + threadIdx.x; k < KP1; k += 512) {
        const float x = ex[k] * rz;
        if (k == 0) part += __logf(x / (x + M_CONST + EPS_C));
        else        part += __logf(M_CONST / (x + M_CONST + EPS_C));
    }
#pragma unroll
    for (int o = 32; o > 0; o >>= 1) part += __shfl_xor(part, o, 64);
    __shared__ float pw[4];
    if ((threadIdx.x & 63) == 0) pw[threadIdx.x >> 6] = part;
    __syncthreads();
    if (threadIdx.x == 0)
        atomicAdd(out, -(pw[0] + pw[1] + pw[2] + pw[3]) * (1.0f / 64.0f));
}

// ---------------------------------------------------------------------------
extern "C" void kernel_launch(void* const* d_in, const int* in_sizes, int n_in,
                              void* d_out, int out_size, void* d_ws, size_t ws_size,
                              hipStream_t stream)
{
    const float* feat_s     = (const float*)d_in[0];
    const float* feat_t     = (const float*)d_in[1];
    /* d_in[2] = idx, unused: sample_idx[:,0] already holds it */
    const int*   sample_idx = (const int*)  d_in[3];
    const float* w_s        = (const float*)d_in[4];
    const float* b_s        = (const float*)d_in[5];
    const float* w_t        = (const float*)d_in[6];
    const float* b_t        = (const float*)d_in[7];
    const float* mem_v1     = (const float*)d_in[8];
    const float* mem_v2     = (const float*)d_in[9];
    float* out = (float*)d_out;

    // Workspace layout:
    //   [z: 128 f32 = 512 B]
    //   [v: 2*64*128 f32 = 64 KB]
    //   [ex: 2*64*16385 f32 = 8.39 MB]
    //   [E: 128*100000 f32 = 51.2 MB]  (transposed: E[sb][n])
    char*  ws    = (char*)d_ws;
    float* ws_z  = (float*)ws;
    float* ws_v  = (float*)(ws + 512);
    float* ws_ex = (float*)(ws + 512 + 2 * BATCH * FEAT * sizeof(float));
    float* ws_E  = (float*)(ws + 512 + 2 * BATCH * FEAT * sizeof(float)
                               + (size_t)2 * BATCH * KP1 * sizeof(float));

    hipMemsetAsync(ws_z, 0, 128 * sizeof(float), stream);
    hipMemsetAsync(out, 0, sizeof(float), stream);

    embed_kernel<<<2 * BATCH, 256, 0, stream>>>(feat_s, feat_t, w_s, b_s, w_t, b_t, ws_v);
    gemm_exp_kernel<<<2 * NTILES, 256, 0, stream>>>(mem_v1, mem_v2, ws_v, ws_E);
    gather_z_kernel<<<2 * BATCH * GCH, 256, 0, stream>>>(sample_idx, ws_E, ws_ex, ws_z);
    loss_kernel<<<2 * BATCH * 2, 256, 0, stream>>>(ws_ex, ws_z, out);
}